// Round 1
// baseline (431.683 us; speedup 1.0000x reference)
//
#include <hip/hip_runtime.h>

// Problem: B=8, S=1024, V=8192, D=256. out[b,s,:] = (x[b,s,:] @ E)*16 + pos[s,:]*any(x[b,s,:])
// GEMM M=8192 K=8192 N=256, A=x (0/1 int32), B=emb. HBM-bound on streaming x (256 MB).

#define M_TOT 8192
#define K_TOT 8192
#define D_DIM 256
#define KSPLIT 4
#define KCHUNK (K_TOT / KSPLIT)   // 2048
#define BK 32

typedef short  short8  __attribute__((ext_vector_type(8)));
typedef float  floatx4 __attribute__((ext_vector_type(4)));
typedef int    intx4   __attribute__((ext_vector_type(4)));

// ws layout: [0, 4MB)          bf16 table, transposed [256][8192], pre-scaled by 16
//            [4MB, 4MB+32KB)   int rowsum[8192]
#define WS_RS_OFF (4u * 1024u * 1024u)

// ---- zero d_out (8 MB) and rowsum (32 KB); both are re-poisoned 0xAA before each run ----
__global__ __launch_bounds__(256) void zero_kernel(float* __restrict__ out, int* __restrict__ rs) {
    int b = blockIdx.x;
    if (b < 2048) {
        floatx4 z = {0.f, 0.f, 0.f, 0.f};
        *(floatx4*)(out + ((size_t)b * 256 + threadIdx.x) * 4) = z;
    } else {
        intx4 z = {0, 0, 0, 0};
        *(intx4*)(rs + ((size_t)(b - 2048) * 256 + threadIdx.x) * 4) = z;
    }
}

// ---- emb [8192][256] fp32 -> wsB [256][8192] bf16, scaled by sqrt(D)=16 (LDS transpose) ----
__global__ __launch_bounds__(256) void prep_kernel(const float* __restrict__ emb,
                                                   unsigned short* __restrict__ wsB) {
    __shared__ unsigned short tile[64][72];   // [d_local][v_local], 144B row stride (16B-aligned)
    int v0 = blockIdx.x * 64, d0 = blockIdx.y * 64;
    int t = threadIdx.x;
    int r = t >> 2, c0 = (t & 3) * 16;
    const float* src = emb + (size_t)(v0 + r) * D_DIM + d0 + c0;
#pragma unroll
    for (int i = 0; i < 16; ++i) {
        unsigned int u = __float_as_uint(src[i] * 16.0f);
        u += 0x7fffu + ((u >> 16) & 1u);              // round-to-nearest-even bf16
        tile[c0 + i][r] = (unsigned short)(u >> 16);  // transpose in LDS
    }
    __syncthreads();
    unsigned short* dst = wsB + (size_t)(d0 + r) * K_TOT + v0 + c0;
#pragma unroll
    for (int i = 0; i < 16; ++i) dst[i] = tile[r][c0 + i];
}

// ---- main GEMM: grid (128 m-blocks, KSPLIT), 256 threads (4 waves of 64x64) ----
__global__ __launch_bounds__(256) void gemm_kernel(const int* __restrict__ x,
                                                   const unsigned short* __restrict__ wsB,
                                                   float* __restrict__ out,
                                                   int* __restrict__ rs) {
    // A tile in LDS, +8 shorts pad => 80B row stride (16B-aligned, 2-way bank alias = free)
    __shared__ unsigned short Al[64][40];

    const int m0   = blockIdx.x * 64;
    const int kbeg = blockIdx.y * KCHUNK;
    const int t    = threadIdx.x;
    const int wave = t >> 6, lane = t & 63;
    const int quad = lane >> 4, rl = lane & 15;
    const int n0   = wave * 64;                 // wave's 64-column slice (waves disjoint in N)

    // staging assignment: thread t loads row t>>2, k-slice (t&3)*8 (8 consecutive int32)
    const int arow = t >> 2, akp = (t & 3) * 8;
    const int* aptr = x + (size_t)(m0 + arow) * K_TOT + kbeg + akp;

    floatx4 acc[4][4];
#pragma unroll
    for (int i = 0; i < 4; ++i)
#pragma unroll
        for (int j = 0; j < 4; ++j) acc[i][j] = (floatx4){0.f, 0.f, 0.f, 0.f};

    int rsum = 0;

    for (int kk = 0; kk < KCHUNK; kk += BK) {
        // A: 8 int32 per thread from HBM (the 256 MB stream, each element read exactly once)
        intx4 a0 = *(const intx4*)aptr;
        intx4 a1 = *(const intx4*)(aptr + 4);
        aptr += BK;

        // B: fragments straight from L2-hot transposed table (no LDS; waves cover disjoint cols)
        short8 bf[4];
#pragma unroll
        for (int j = 0; j < 4; ++j) {
            const unsigned short* bp = wsB + (size_t)(n0 + j * 16 + rl) * K_TOT + kbeg + kk + quad * 8;
            bf[j] = *(const short8*)bp;   // 16B contiguous: B[k=quad*8+jj][n=rl] layout
        }

        // int -> bf16 (x in {0,1}: 1.0f bf16 = 0x3F80), fused row-sum
        short8 av;
#pragma unroll
        for (int i = 0; i < 4; ++i) { av[i]     = a0[i] ? (short)0x3F80 : (short)0; rsum += a0[i]; }
#pragma unroll
        for (int i = 0; i < 4; ++i) { av[4 + i] = a1[i] ? (short)0x3F80 : (short)0; rsum += a1[i]; }

        __syncthreads();                         // prior iter's Al reads done
        *(short8*)&Al[arow][akp] = av;
        __syncthreads();

        short8 af[4];
#pragma unroll
        for (int i = 0; i < 4; ++i)
            af[i] = *(const short8*)&Al[i * 16 + rl][quad * 8];   // A[m=rl][k=quad*8+jj]

#pragma unroll
        for (int i = 0; i < 4; ++i)
#pragma unroll
            for (int j = 0; j < 4; ++j)
                acc[i][j] = __builtin_amdgcn_mfma_f32_16x16x32_bf16(af[i], bf[j], acc[i][j], 0, 0, 0);
    }

    // row-sum: reduce the 4 k-slice threads per row (consecutive lanes), one atomic per row
    rsum += __shfl_down(rsum, 1);
    rsum += __shfl_down(rsum, 2);
    if ((t & 3) == 0) atomicAdd(&rs[m0 + arow], rsum);

    // C/D layout: col = lane&15, row = quad*4 + reg (m89-verified). Atomic-accumulate K-partials.
#pragma unroll
    for (int i = 0; i < 4; ++i) {
#pragma unroll
        for (int j = 0; j < 4; ++j) {
            int col = n0 + j * 16 + rl;
#pragma unroll
            for (int r = 0; r < 4; ++r) {
                int row = m0 + i * 16 + quad * 4 + r;
                unsafeAtomicAdd(&out[(size_t)row * D_DIM + col], acc[i][j][r]);
            }
        }
    }
}

// ---- epilogue: out[m,:] += pos[m%1024,:] where rowsum[m] > 0 ----
__global__ __launch_bounds__(256) void epi_kernel(float* __restrict__ out,
                                                  const float* __restrict__ pos,
                                                  const int* __restrict__ rs) {
    int gid  = blockIdx.x * 256 + threadIdx.x;
    int base = gid * 4;                 // 4 floats per thread, col group stays within one row
    int row  = base >> 8;
    int col  = base & 255;
    if (rs[row] > 0) {
        int s = row & 1023;             // m = b*1024 + s
        floatx4 o = *(floatx4*)(out + base);
        floatx4 p = *(const floatx4*)(pos + (size_t)s * D_DIM + col);
        o += p;
        *(floatx4*)(out + base) = o;
    }
}

extern "C" void kernel_launch(void* const* d_in, const int* in_sizes, int n_in,
                              void* d_out, int out_size, void* d_ws, size_t ws_size,
                              hipStream_t stream) {
    const int*   x   = (const int*)d_in[0];     // [8,1024,8192] int32
    const float* emb = (const float*)d_in[1];   // [8192,256] fp32
    const float* pos = (const float*)d_in[2];   // [1,1024,256] fp32
    float*       out = (float*)d_out;           // [8,1024,256] fp32

    unsigned short* wsB = (unsigned short*)d_ws;                 // 4 MB bf16 table (transposed)
    int*            rs  = (int*)((char*)d_ws + WS_RS_OFF);       // 32 KB row sums

    zero_kernel<<<dim3(2056), dim3(256), 0, stream>>>(out, rs);
    prep_kernel<<<dim3(128, 4), dim3(256), 0, stream>>>(emb, wsB);
    gemm_kernel<<<dim3(128, KSPLIT), dim3(256), 0, stream>>>(x, wsB, out, rs);
    epi_kernel<<<dim3(2048), dim3(256), 0, stream>>>(out, pos, rs);
}